// Round 5
// baseline (514.248 us; speedup 1.0000x reference)
//
#include <hip/hip_runtime.h>
#include <hip/hip_bf16.h>
#include <hip/hip_cooperative_groups.h>

namespace cg = cooperative_groups;

#define N_PTS 16384
#define TEMP_F 0.05f

typedef __attribute__((ext_vector_type(8))) short bf16x8;
typedef __attribute__((ext_vector_type(4))) float f32x4;

__device__ __forceinline__ float selu_f(float x) {
    const float scale = 1.0507009873554805f;
    const float alpha = 1.6732632423543772f;
    return x > 0.f ? scale * x : scale * alpha * (__expf(x) - 1.f);
}

__device__ __forceinline__ float fast_sqrtf(float x) {
#if __has_builtin(__builtin_amdgcn_sqrtf)
    return __builtin_amdgcn_sqrtf(x);   // v_sqrt_f32
#else
    return sqrtf(x);
#endif
}

__device__ __forceinline__ float fast_exp2f(float x) {
#if __has_builtin(__builtin_amdgcn_exp2f)
    return __builtin_amdgcn_exp2f(x);   // v_exp_f32
#else
    return exp2f(x);
#endif
}

__device__ __forceinline__ float fast_log2f(float x) {
#if __has_builtin(__builtin_amdgcn_logf)
    return __builtin_amdgcn_logf(x);    // v_log_f32
#else
    return log2f(x);
#endif
}

__device__ __forceinline__ f32x4 mfma_bf16(bf16x8 a, bf16x8 b, f32x4 c) {
    return __builtin_amdgcn_mfma_f32_16x16x32_bf16(a, b, c, 0, 0, 0);
}

// split fp32 v into truncated-bf16 hi + bf16(residual) lo; hi+lo ~ 16-bit mantissa
__device__ __forceinline__ void split_bf16(float v, unsigned short& hi, unsigned short& lo) {
    unsigned u = __float_as_uint(v);
    hi = (unsigned short)(u >> 16);
    float ah = __uint_as_float(u & 0xFFFF0000u);
    lo = (unsigned short)(__float_as_uint(v - ah) >> 16);
}

// ===========================================================================
// FUSED cooperative kernel: pack -> gridsync -> MLP -> gridsync -> energy.
// 512 blocks x 512 threads, __launch_bounds__(512,4) (<=128 VGPR), 48KB LDS
// -> exactly 2 blocks/CU co-resident (16 waves/CU). ONE dispatch per iter.
// All arithmetic bit-identical to the round-3/4 kernels.
// ===========================================================================
__global__ __launch_bounds__(512, 4) void fused_kernel(
    const float* pos, const float* z,
    const float* W1, const float* b1, const float* W2, const float* b2,
    const float* W3, const float* b3, const float* W4, const float* b4,
    const float* W5, const float* b5,
    unsigned short* pk, float* gen, float* out)
{
    __shared__ __align__(16) unsigned short Hh[32 * 256];   // 16 KB
    __shared__ __align__(16) unsigned short Hl[32 * 256];   // 16 KB
    __shared__ float4 sp[512];                              //  8 KB
    __shared__ float4 sg[512];                              //  8 KB

    const int t = threadIdx.x;

    // ---------------- phase 0: pack (blocks 0..49, 25600 threads) ----------
    if (blockIdx.x < 50) {
        int idx = blockIdx.x * 512 + t;          // 0..25599
        const float* src;
        unsigned short *dh, *dl;
        int nt, kc, lx, KC;
        if (idx < 1024) {                        // W1: K=32, KC=1
            src = W1; dh = pk; dl = pk + 8192; KC = 1;
            nt = idx >> 6; kc = 0; lx = idx & 63;
        } else {                                 // W2..W4: K=256, KC=8
            int t2 = idx - 1024;
            int ly = t2 >> 13;                   // /8192
            int r2 = t2 & 8191;
            src = (ly == 0) ? W2 : (ly == 1) ? W3 : W4;
            dh = pk + 16384 + ly * 131072;
            dl = dh + 65536;
            KC = 8;
            nt = r2 >> 9; kc = (r2 >> 6) & 7; lx = r2 & 63;
        }
        int lrp = lx & 15, lqp = lx >> 4;
        int n = nt * 16 + lrp;
        bf16x8 hv, lv;
        #pragma unroll
        for (int e = 0; e < 8; e++) {
            int k = kc * 32 + lqp * 8 + e;
            float v = src[k * 256 + n];
            unsigned short hb, lb;
            split_bf16(v, hb, lb);
            hv[e] = (short)hb; lv[e] = (short)lb;
        }
        int basep = ((nt * KC + kc) * 64 + lx) * 8;
        *(bf16x8*)(dh + basep) = hv;
        *(bf16x8*)(dl + basep) = lv;
    }
    __threadfence();
    cg::this_grid().sync();

    // ---------------- phase 1: MLP (v3 body, 32 rows/block, 512 blocks) ----
    {
        const int l  = t & 63;
        const int wv = t >> 6;          // 0..7: owns n-tiles {2wv, 2wv+1}
        const int lr = l & 15;          // fragment m (A) / n (B,D) index
        const int lq = l >> 4;          // 0..3: k-subblock / D row group
        const int row0 = blockIdx.x * 32;

        f32x4 acc[2][2];

        // ---- layer 1 (32 -> 256), K fits one MFMA ----
        {
            bf16x8 ah[2], al[2];
            #pragma unroll
            for (int m = 0; m < 2; m++) {
                const float* zp = z + (row0 + m * 16 + lr) * 32 + lq * 8;
                f32x4 z0 = *(const f32x4*)(zp);
                f32x4 z1 = *(const f32x4*)(zp + 4);
                #pragma unroll
                for (int e = 0; e < 8; e++) {
                    float v = (e < 4) ? z0[e] : z1[e - 4];
                    unsigned short hb, lb;
                    split_bf16(v, hb, lb);
                    ah[m][e] = (short)hb; al[m][e] = (short)lb;
                }
            }
            #pragma unroll
            for (int n2 = 0; n2 < 2; n2++) {
                float bv = b1[wv * 32 + n2 * 16 + lr];
                #pragma unroll
                for (int m = 0; m < 2; m++) acc[m][n2] = (f32x4){bv, bv, bv, bv};
            }
            const bf16x8* B1h = (const bf16x8*)(pk);
            const bf16x8* B1l = (const bf16x8*)(pk + 8192);
            #pragma unroll
            for (int n2 = 0; n2 < 2; n2++) {
                int nt = wv * 2 + n2;
                bf16x8 bh = B1h[nt * 64 + l];
                bf16x8 bl = B1l[nt * 64 + l];
                #pragma unroll
                for (int m = 0; m < 2; m++) {
                    acc[m][n2] = mfma_bf16(ah[m], bh, acc[m][n2]);
                    acc[m][n2] = mfma_bf16(ah[m], bl, acc[m][n2]);
                    acc[m][n2] = mfma_bf16(al[m], bh, acc[m][n2]);
                }
            }
            // D layout (verified m89): col = lane&15, row = (lane>>4)*4 + r
            #pragma unroll
            for (int m = 0; m < 2; m++) {
                #pragma unroll
                for (int n2 = 0; n2 < 2; n2++) {
                    #pragma unroll
                    for (int r = 0; r < 4; r++) {
                        float v = selu_f(acc[m][n2][r]);
                        int rowo = m * 16 + lq * 4 + r;
                        int n = wv * 32 + n2 * 16 + lr;
                        int o = (2 * n) ^ ((rowo & 7) << 4);
                        unsigned short hb, lb;
                        split_bf16(v, hb, lb);
                        Hh[rowo * 256 + (o >> 1)] = hb;
                        Hl[rowo * 256 + (o >> 1)] = lb;
                    }
                }
            }
        }
        __syncthreads();

        // ---- layers 2..4 (256 -> 256) ----
        #pragma unroll 1
        for (int ly = 0; ly < 3; ly++) {
            const unsigned short* wbase = pk + 16384 + ly * 131072;
            const bf16x8* Bh = (const bf16x8*)(wbase);
            const bf16x8* Bl = (const bf16x8*)(wbase + 65536);
            const float* bb = (ly == 0) ? b2 : (ly == 1) ? b3 : b4;
            #pragma unroll
            for (int n2 = 0; n2 < 2; n2++) {
                float bv = bb[wv * 32 + n2 * 16 + lr];
                #pragma unroll
                for (int m = 0; m < 2; m++) acc[m][n2] = (f32x4){bv, bv, bv, bv};
            }
            #pragma unroll 4
            for (int kc = 0; kc < 8; kc++) {
                bf16x8 ah[2], al[2];
                #pragma unroll
                for (int m = 0; m < 2; m++) {
                    int arow = m * 16 + lr;
                    int o = (kc * 64 + lq * 16) ^ ((arow & 7) << 4);
                    ah[m] = *(const bf16x8*)(Hh + arow * 256 + (o >> 1));
                    al[m] = *(const bf16x8*)(Hl + arow * 256 + (o >> 1));
                }
                #pragma unroll
                for (int n2 = 0; n2 < 2; n2++) {
                    bf16x8 bh = Bh[((wv * 2 + n2) * 8 + kc) * 64 + l];
                    bf16x8 bl = Bl[((wv * 2 + n2) * 8 + kc) * 64 + l];
                    #pragma unroll
                    for (int m = 0; m < 2; m++) {
                        acc[m][n2] = mfma_bf16(ah[m], bh, acc[m][n2]);
                        acc[m][n2] = mfma_bf16(ah[m], bl, acc[m][n2]);
                        acc[m][n2] = mfma_bf16(al[m], bh, acc[m][n2]);
                    }
                }
            }
            __syncthreads();   // all waves done READING H before overwrite
            #pragma unroll
            for (int m = 0; m < 2; m++) {
                #pragma unroll
                for (int n2 = 0; n2 < 2; n2++) {
                    #pragma unroll
                    for (int r = 0; r < 4; r++) {
                        float v = selu_f(acc[m][n2][r]);
                        int rowo = m * 16 + lq * 4 + r;
                        int n = wv * 32 + n2 * 16 + lr;
                        int o = (2 * n) ^ ((rowo & 7) << 4);
                        unsigned short hb, lb;
                        split_bf16(v, hb, lb);
                        Hh[rowo * 256 + (o >> 1)] = hb;
                        Hl[rowo * 256 + (o >> 1)] = lb;
                    }
                }
            }
            __syncthreads();
        }

        // ---- layer 5 (256 -> 2), VALU, 64 threads ----
        if (t < 64) {
            int row = t & 31;
            int d = t >> 5;
            float sum = b5[d];
            #pragma unroll 4
            for (int k = 0; k < 256; k += 8) {
                int o = (2 * k) ^ ((row & 7) << 4);
                bf16x8 hh = *(const bf16x8*)(Hh + row * 256 + (o >> 1));
                bf16x8 ll = *(const bf16x8*)(Hl + row * 256 + (o >> 1));
                #pragma unroll
                for (int e = 0; e < 8; e++) {
                    float hv = __uint_as_float(((unsigned)(unsigned short)hh[e]) << 16)
                             + __uint_as_float(((unsigned)(unsigned short)ll[e]) << 16);
                    sum = fmaf(hv, W5[(k + e) * 2 + d], sum);
                }
            }
            gen[(row0 + row) * 2 + d] = sum;
        }
    }
    __threadfence();
    cg::this_grid().sync();

    // ---------------- phase 2: energy, 2 row-chunks per block --------------
    {
        const int s  = t & 31;       // lane within row-group
        const int rl = t >> 5;       // 0..15 row within block

        const float cL2 = 28.853900817779268f;   // 1/(T*ln2) = 20*log2(e)
        const float Tl2 = 0.034657359027997264f; // T*ln2
        const float cB  = 57.707801635558536f;   // cL2 * B, B = 2.0

        #pragma unroll 1
        for (int c = 0; c < 2; c++) {
            const int row_off = c * 8192;
            const int i = row_off + blockIdx.x * 16 + rl;
            const int diagBase = ((row_off + blockIdx.x * 16) >> 10) << 10;

            const float2 q = ((const float2*)gen)[i];
            float p0 = 0.f, p1 = 0.f, n0 = 0.f, n1 = 0.f;

            for (int base = 0; base < N_PTS; base += 1024) {
                __syncthreads();
                sp[t] = ((const float4*)pos)[base / 2 + t];
                sg[t] = ((const float4*)gen)[base / 2 + t];
                __syncthreads();
                if (base == diagBase) {
                    #pragma unroll 4
                    for (int u = 0; u < 16; u++) {
                        int j = base + 2 * (s + 32 * u);
                        float4 pp = sp[s + 32 * u];
                        float4 gg = sg[s + 32 * u];
                        float dx = q.x - pp.x, dy = q.y - pp.y;
                        float d  = fast_sqrtf(fmaf(dx, dx, dy * dy));
                        p0 += fast_exp2f(fmaf(-cL2, d, cB));
                        dx = q.x - pp.z; dy = q.y - pp.w;
                        d  = fast_sqrtf(fmaf(dx, dx, dy * dy));
                        p1 += fast_exp2f(fmaf(-cL2, d, cB));
                        dx = q.x - gg.x; dy = q.y - gg.y;
                        d  = fast_sqrtf(fmaf(dx, dx, dy * dy));
                        float e0 = fast_exp2f(fmaf(-cL2, d, cB));
                        n0 += (j == i) ? 0.f : e0;
                        dx = q.x - gg.z; dy = q.y - gg.w;
                        d  = fast_sqrtf(fmaf(dx, dx, dy * dy));
                        float e1 = fast_exp2f(fmaf(-cL2, d, cB));
                        n1 += (j + 1 == i) ? 0.f : e1;
                    }
                } else {
                    #pragma unroll 4
                    for (int u = 0; u < 16; u++) {
                        float4 pp = sp[s + 32 * u];
                        float4 gg = sg[s + 32 * u];
                        float dx = q.x - pp.x, dy = q.y - pp.y;
                        float d  = fast_sqrtf(fmaf(dx, dx, dy * dy));
                        p0 += fast_exp2f(fmaf(-cL2, d, cB));
                        dx = q.x - pp.z; dy = q.y - pp.w;
                        d  = fast_sqrtf(fmaf(dx, dx, dy * dy));
                        p1 += fast_exp2f(fmaf(-cL2, d, cB));
                        dx = q.x - gg.x; dy = q.y - gg.y;
                        d  = fast_sqrtf(fmaf(dx, dx, dy * dy));
                        n0 += fast_exp2f(fmaf(-cL2, d, cB));
                        dx = q.x - gg.z; dy = q.y - gg.w;
                        d  = fast_sqrtf(fmaf(dx, dx, dy * dy));
                        n1 += fast_exp2f(fmaf(-cL2, d, cB));
                    }
                }
            }

            float sump = p0 + p1;
            float sumn = n0 + n1;
            #pragma unroll
            for (int m = 1; m < 32; m <<= 1) {
                sump += __shfl_xor(sump, m, 32);
                sumn += __shfl_xor(sumn, m, 32);
            }
            if (s == 0) {
                out[i] = Tl2 * (fast_log2f(sumn) - fast_log2f(sump));
            }
            __syncthreads();   // sp/sg reuse safety between chunks
        }
    }
}

// ===========================================================================
// Standalone kernels (fallback path if cooperative launch unavailable)
// ===========================================================================

__global__ __launch_bounds__(256) void pack_kernel(
    const float* __restrict__ W1, const float* __restrict__ W2,
    const float* __restrict__ W3, const float* __restrict__ W4,
    unsigned short* __restrict__ pk)
{
    int idx = blockIdx.x * 256 + threadIdx.x;   // 0..25599
    if (idx >= 25600) return;
    const float* src;
    unsigned short *dh, *dl;
    int nt, kc, l, KC;
    if (idx < 1024) {
        src = W1; dh = pk; dl = pk + 8192; KC = 1;
        nt = idx >> 6; kc = 0; l = idx & 63;
    } else {
        int t2 = idx - 1024;
        int ly = t2 >> 13;
        int r2 = t2 & 8191;
        src = (ly == 0) ? W2 : (ly == 1) ? W3 : W4;
        dh = pk + 16384 + ly * 131072;
        dl = dh + 65536;
        KC = 8;
        nt = r2 >> 9; kc = (r2 >> 6) & 7; l = r2 & 63;
    }
    int lr = l & 15, lq = l >> 4;
    int n = nt * 16 + lr;
    bf16x8 hv, lv;
    #pragma unroll
    for (int e = 0; e < 8; e++) {
        int k = kc * 32 + lq * 8 + e;
        float v = src[k * 256 + n];
        unsigned short hb, lb;
        split_bf16(v, hb, lb);
        hv[e] = (short)hb; lv[e] = (short)lb;
    }
    int base = ((nt * KC + kc) * 64 + l) * 8;
    *(bf16x8*)(dh + base) = hv;
    *(bf16x8*)(dl + base) = lv;
}

__global__ __launch_bounds__(512) void mlp_mfma_kernel(
    const float* __restrict__ z,
    const unsigned short* __restrict__ pk,
    const float* __restrict__ b1, const float* __restrict__ b2,
    const float* __restrict__ b3, const float* __restrict__ b4,
    const float* __restrict__ W5, const float* __restrict__ b5,
    float* __restrict__ gen)
{
    __shared__ __align__(16) unsigned short Hh[32 * 256];
    __shared__ __align__(16) unsigned short Hl[32 * 256];

    const int t  = threadIdx.x;
    const int l  = t & 63;
    const int wv = t >> 6;
    const int lr = l & 15;
    const int lq = l >> 4;
    const int row0 = blockIdx.x * 32;

    f32x4 acc[2][2];

    {
        bf16x8 ah[2], al[2];
        #pragma unroll
        for (int m = 0; m < 2; m++) {
            const float* zp = z + (row0 + m * 16 + lr) * 32 + lq * 8;
            f32x4 z0 = *(const f32x4*)(zp);
            f32x4 z1 = *(const f32x4*)(zp + 4);
            #pragma unroll
            for (int e = 0; e < 8; e++) {
                float v = (e < 4) ? z0[e] : z1[e - 4];
                unsigned short hb, lb;
                split_bf16(v, hb, lb);
                ah[m][e] = (short)hb; al[m][e] = (short)lb;
            }
        }
        #pragma unroll
        for (int n2 = 0; n2 < 2; n2++) {
            float bv = b1[wv * 32 + n2 * 16 + lr];
            #pragma unroll
            for (int m = 0; m < 2; m++) acc[m][n2] = (f32x4){bv, bv, bv, bv};
        }
        const bf16x8* B1h = (const bf16x8*)(pk);
        const bf16x8* B1l = (const bf16x8*)(pk + 8192);
        #pragma unroll
        for (int n2 = 0; n2 < 2; n2++) {
            int nt = wv * 2 + n2;
            bf16x8 bh = B1h[nt * 64 + l];
            bf16x8 bl = B1l[nt * 64 + l];
            #pragma unroll
            for (int m = 0; m < 2; m++) {
                acc[m][n2] = mfma_bf16(ah[m], bh, acc[m][n2]);
                acc[m][n2] = mfma_bf16(ah[m], bl, acc[m][n2]);
                acc[m][n2] = mfma_bf16(al[m], bh, acc[m][n2]);
            }
        }
        #pragma unroll
        for (int m = 0; m < 2; m++) {
            #pragma unroll
            for (int n2 = 0; n2 < 2; n2++) {
                #pragma unroll
                for (int r = 0; r < 4; r++) {
                    float v = selu_f(acc[m][n2][r]);
                    int rowo = m * 16 + lq * 4 + r;
                    int n = wv * 32 + n2 * 16 + lr;
                    int o = (2 * n) ^ ((rowo & 7) << 4);
                    unsigned short hb, lb;
                    split_bf16(v, hb, lb);
                    Hh[rowo * 256 + (o >> 1)] = hb;
                    Hl[rowo * 256 + (o >> 1)] = lb;
                }
            }
        }
    }
    __syncthreads();

    #pragma unroll 1
    for (int ly = 0; ly < 3; ly++) {
        const unsigned short* wbase = pk + 16384 + ly * 131072;
        const bf16x8* Bh = (const bf16x8*)(wbase);
        const bf16x8* Bl = (const bf16x8*)(wbase + 65536);
        const float* bb = (ly == 0) ? b2 : (ly == 1) ? b3 : b4;
        #pragma unroll
        for (int n2 = 0; n2 < 2; n2++) {
            float bv = bb[wv * 32 + n2 * 16 + lr];
            #pragma unroll
            for (int m = 0; m < 2; m++) acc[m][n2] = (f32x4){bv, bv, bv, bv};
        }
        #pragma unroll 4
        for (int kc = 0; kc < 8; kc++) {
            bf16x8 ah[2], al[2];
            #pragma unroll
            for (int m = 0; m < 2; m++) {
                int arow = m * 16 + lr;
                int o = (kc * 64 + lq * 16) ^ ((arow & 7) << 4);
                ah[m] = *(const bf16x8*)(Hh + arow * 256 + (o >> 1));
                al[m] = *(const bf16x8*)(Hl + arow * 256 + (o >> 1));
            }
            #pragma unroll
            for (int n2 = 0; n2 < 2; n2++) {
                bf16x8 bh = Bh[((wv * 2 + n2) * 8 + kc) * 64 + l];
                bf16x8 bl = Bl[((wv * 2 + n2) * 8 + kc) * 64 + l];
                #pragma unroll
                for (int m = 0; m < 2; m++) {
                    acc[m][n2] = mfma_bf16(ah[m], bh, acc[m][n2]);
                    acc[m][n2] = mfma_bf16(ah[m], bl, acc[m][n2]);
                    acc[m][n2] = mfma_bf16(al[m], bh, acc[m][n2]);
                }
            }
        }
        __syncthreads();
        #pragma unroll
        for (int m = 0; m < 2; m++) {
            #pragma unroll
            for (int n2 = 0; n2 < 2; n2++) {
                #pragma unroll
                for (int r = 0; r < 4; r++) {
                    float v = selu_f(acc[m][n2][r]);
                    int rowo = m * 16 + lq * 4 + r;
                    int n = wv * 32 + n2 * 16 + lr;
                    int o = (2 * n) ^ ((rowo & 7) << 4);
                    unsigned short hb, lb;
                    split_bf16(v, hb, lb);
                    Hh[rowo * 256 + (o >> 1)] = hb;
                    Hl[rowo * 256 + (o >> 1)] = lb;
                }
            }
        }
        __syncthreads();
    }

    if (t < 64) {
        int row = t & 31;
        int d = t >> 5;
        float sum = b5[d];
        #pragma unroll 4
        for (int k = 0; k < 256; k += 8) {
            int o = (2 * k) ^ ((row & 7) << 4);
            bf16x8 hh = *(const bf16x8*)(Hh + row * 256 + (o >> 1));
            bf16x8 ll = *(const bf16x8*)(Hl + row * 256 + (o >> 1));
            #pragma unroll
            for (int e = 0; e < 8; e++) {
                float hv = __uint_as_float(((unsigned)(unsigned short)hh[e]) << 16)
                         + __uint_as_float(((unsigned)(unsigned short)ll[e]) << 16);
                sum = fmaf(hv, W5[(k + e) * 2 + d], sum);
            }
        }
        gen[(row0 + row) * 2 + d] = sum;
    }
}

__global__ __launch_bounds__(1024) void mlp_kernel(
    const float* __restrict__ z,
    const float* __restrict__ W1, const float* __restrict__ b1,
    const float* __restrict__ W2, const float* __restrict__ b2,
    const float* __restrict__ W3, const float* __restrict__ b3,
    const float* __restrict__ W4, const float* __restrict__ b4,
    const float* __restrict__ W5, const float* __restrict__ b5,
    float* __restrict__ gen)
{
    __shared__ float h[256 * 64];

    const int t = threadIdx.x;
    const int r = t & 63;
    const int w = __builtin_amdgcn_readfirstlane(t >> 6);
    const int c0 = w * 16;
    const int row0 = blockIdx.x * 64;

    #pragma unroll
    for (int e = 0; e < 2; e++) {
        int f  = t + e * 1024;
        int rz = f >> 5;
        int kz = f & 31;
        h[kz * 64 + rz] = z[(row0 + rz) * 32 + kz];
    }
    __syncthreads();

    float acc[16];

    #pragma unroll
    for (int j = 0; j < 16; j++) acc[j] = b1[c0 + j];
    #pragma unroll 8
    for (int k = 0; k < 32; k++) {
        float hv = h[k * 64 + r];
        const float* Wr = W1 + k * 256 + c0;
        #pragma unroll
        for (int j = 0; j < 16; j++) acc[j] = fmaf(hv, Wr[j], acc[j]);
    }
    __syncthreads();
    #pragma unroll
    for (int j = 0; j < 16; j++) h[(c0 + j) * 64 + r] = selu_f(acc[j]);
    __syncthreads();

    for (int layer = 0; layer < 3; layer++) {
        const float* W = (layer == 0) ? W2 : (layer == 1) ? W3 : W4;
        const float* b = (layer == 0) ? b2 : (layer == 1) ? b3 : b4;
        #pragma unroll
        for (int j = 0; j < 16; j++) acc[j] = b[c0 + j];
        #pragma unroll 4
        for (int k = 0; k < 256; k++) {
            float hv = h[k * 64 + r];
            const float* Wr = W + k * 256 + c0;
            #pragma unroll
            for (int j = 0; j < 16; j++) acc[j] = fmaf(hv, Wr[j], acc[j]);
        }
        __syncthreads();
        #pragma unroll
        for (int j = 0; j < 16; j++) h[(c0 + j) * 64 + r] = selu_f(acc[j]);
        __syncthreads();
    }

    float p0 = 0.f, p1 = 0.f;
    #pragma unroll
    for (int kk = 0; kk < 16; kk++) {
        int k = c0 + kk;
        float hv = h[k * 64 + r];
        p0 = fmaf(hv, W5[k * 2 + 0], p0);
        p1 = fmaf(hv, W5[k * 2 + 1], p1);
    }
    __syncthreads();
    h[(0 * 16 + w) * 64 + r] = p0;
    h[(1 * 16 + w) * 64 + r] = p1;
    __syncthreads();
    if (t < 128) {
        int d  = t >> 6;
        int rr = t & 63;
        float sum = b5[d];
        #pragma unroll
        for (int ss = 0; ss < 16; ss++) sum += h[(d * 16 + ss) * 64 + rr];
        gen[(row0 + rr) * 2 + d] = sum;
    }
}

__global__ __launch_bounds__(512) void energy_kernel(
    const float* __restrict__ gen,
    const float* __restrict__ pos,
    float* __restrict__ out,
    int row_off)
{
    __shared__ float4 sp[512];
    __shared__ float4 sg[512];

    const int t  = threadIdx.x;
    const int s  = t & 31;
    const int rl = t >> 5;
    const int i  = row_off + blockIdx.x * 16 + rl;
    const int diagBase = ((row_off + blockIdx.x * 16) >> 10) << 10;

    const float2 q = ((const float2*)gen)[i];

    const float cL2 = 28.853900817779268f;
    const float Tl2 = 0.034657359027997264f;
    const float cB  = 57.707801635558536f;

    float p0 = 0.f, p1 = 0.f, n0 = 0.f, n1 = 0.f;

    for (int base = 0; base < N_PTS; base += 1024) {
        __syncthreads();
        sp[t] = ((const float4*)pos)[base / 2 + t];
        sg[t] = ((const float4*)gen)[base / 2 + t];
        __syncthreads();
        if (base == diagBase) {
            #pragma unroll 4
            for (int u = 0; u < 16; u++) {
                int j = base + 2 * (s + 32 * u);
                float4 pp = sp[s + 32 * u];
                float4 gg = sg[s + 32 * u];
                float dx = q.x - pp.x, dy = q.y - pp.y;
                float d  = fast_sqrtf(fmaf(dx, dx, dy * dy));
                p0 += fast_exp2f(fmaf(-cL2, d, cB));
                dx = q.x - pp.z; dy = q.y - pp.w;
                d  = fast_sqrtf(fmaf(dx, dx, dy * dy));
                p1 += fast_exp2f(fmaf(-cL2, d, cB));
                dx = q.x - gg.x; dy = q.y - gg.y;
                d  = fast_sqrtf(fmaf(dx, dx, dy * dy));
                float e0 = fast_exp2f(fmaf(-cL2, d, cB));
                n0 += (j == i) ? 0.f : e0;
                dx = q.x - gg.z; dy = q.y - gg.w;
                d  = fast_sqrtf(fmaf(dx, dx, dy * dy));
                float e1 = fast_exp2f(fmaf(-cL2, d, cB));
                n1 += (j + 1 == i) ? 0.f : e1;
            }
        } else {
            #pragma unroll 4
            for (int u = 0; u < 16; u++) {
                float4 pp = sp[s + 32 * u];
                float4 gg = sg[s + 32 * u];
                float dx = q.x - pp.x, dy = q.y - pp.y;
                float d  = fast_sqrtf(fmaf(dx, dx, dy * dy));
                p0 += fast_exp2f(fmaf(-cL2, d, cB));
                dx = q.x - pp.z; dy = q.y - pp.w;
                d  = fast_sqrtf(fmaf(dx, dx, dy * dy));
                p1 += fast_exp2f(fmaf(-cL2, d, cB));
                dx = q.x - gg.x; dy = q.y - gg.y;
                d  = fast_sqrtf(fmaf(dx, dx, dy * dy));
                n0 += fast_exp2f(fmaf(-cL2, d, cB));
                dx = q.x - gg.z; dy = q.y - gg.w;
                d  = fast_sqrtf(fmaf(dx, dx, dy * dy));
                n1 += fast_exp2f(fmaf(-cL2, d, cB));
            }
        }
    }

    float sump = p0 + p1;
    float sumn = n0 + n1;
    #pragma unroll
    for (int m = 1; m < 32; m <<= 1) {
        sump += __shfl_xor(sump, m, 32);
        sumn += __shfl_xor(sumn, m, 32);
    }

    if (s == 0) {
        out[i] = Tl2 * (fast_log2f(sumn) - fast_log2f(sump));
    }
}

// ---------------------------------------------------------------------------
extern "C" void kernel_launch(void* const* d_in, const int* in_sizes, int n_in,
                              void* d_out, int out_size, void* d_ws, size_t ws_size,
                              hipStream_t stream) {
    const float* pos = (const float*)d_in[0];
    const float* z   = (const float*)d_in[1];
    const float* W1  = (const float*)d_in[2];
    const float* b1  = (const float*)d_in[3];
    const float* W2  = (const float*)d_in[4];
    const float* b2  = (const float*)d_in[5];
    const float* W3  = (const float*)d_in[6];
    const float* b3  = (const float*)d_in[7];
    const float* W4  = (const float*)d_in[8];
    const float* b4  = (const float*)d_in[9];
    const float* W5  = (const float*)d_in[10];
    const float* b5  = (const float*)d_in[11];

    float* gen = (float*)d_ws;                               // 16384 x 2 fp32
    unsigned short* pk = (unsigned short*)((char*)d_ws + 131072);
    float* outp = (float*)d_out;
    const size_t WS_NEEDED = 131072 + (size_t)409600 * 2;    // gen + packed W

    if (ws_size >= WS_NEEDED) {
        void* args[] = {
            (void*)&pos, (void*)&z,
            (void*)&W1, (void*)&b1, (void*)&W2, (void*)&b2,
            (void*)&W3, (void*)&b3, (void*)&W4, (void*)&b4,
            (void*)&W5, (void*)&b5,
            (void*)&pk, (void*)&gen, (void*)&outp
        };
        hipError_t err = hipLaunchCooperativeKernel(
            reinterpret_cast<void*>(fused_kernel),
            dim3(512), dim3(512), args, 0, stream);
        if (err == hipSuccess) return;
        // fall through to the 3-kernel path if cooperative launch rejected
        pack_kernel<<<100, 256, 0, stream>>>(W1, W2, W3, W4, pk);
        mlp_mfma_kernel<<<N_PTS / 32, 512, 0, stream>>>(z, pk, b1, b2, b3, b4,
                                                        W5, b5, gen);
        energy_kernel<<<N_PTS / 16, 512, 0, stream>>>(gen, pos, outp, 0);
    } else {
        mlp_kernel<<<N_PTS / 64, 1024, 0, stream>>>(z, W1, b1, W2, b2, W3, b3,
                                                    W4, b4, W5, b5, gen);
        energy_kernel<<<N_PTS / 16, 512, 0, stream>>>(gen, pos, outp, 0);
    }
}

// Round 6
// 271.188 us; speedup vs baseline: 1.8963x; 1.8963x over previous
//
#include <hip/hip_runtime.h>
#include <hip/hip_bf16.h>

#define N_PTS 16384
#define TEMP_F 0.05f

typedef __attribute__((ext_vector_type(8))) short bf16x8;
typedef __attribute__((ext_vector_type(4))) float f32x4;

__device__ __forceinline__ float selu_f(float x) {
    const float scale = 1.0507009873554805f;
    const float alpha = 1.6732632423543772f;
    return x > 0.f ? scale * x : scale * alpha * (__expf(x) - 1.f);
}

__device__ __forceinline__ float fast_sqrtf(float x) {
#if __has_builtin(__builtin_amdgcn_sqrtf)
    return __builtin_amdgcn_sqrtf(x);   // v_sqrt_f32
#else
    return sqrtf(x);
#endif
}

__device__ __forceinline__ float fast_exp2f(float x) {
#if __has_builtin(__builtin_amdgcn_exp2f)
    return __builtin_amdgcn_exp2f(x);   // v_exp_f32
#else
    return exp2f(x);
#endif
}

__device__ __forceinline__ float fast_log2f(float x) {
#if __has_builtin(__builtin_amdgcn_logf)
    return __builtin_amdgcn_logf(x);    // v_log_f32
#else
    return log2f(x);
#endif
}

__device__ __forceinline__ f32x4 mfma_bf16(bf16x8 a, bf16x8 b, f32x4 c) {
    return __builtin_amdgcn_mfma_f32_16x16x32_bf16(a, b, c, 0, 0, 0);
}

// split fp32 v into truncated-bf16 hi + bf16(residual) lo; hi+lo ~ 16-bit mantissa
__device__ __forceinline__ void split_bf16(float v, unsigned short& hi, unsigned short& lo) {
    unsigned u = __float_as_uint(v);
    hi = (unsigned short)(u >> 16);
    float ah = __uint_as_float(u & 0xFFFF0000u);
    lo = (unsigned short)(__float_as_uint(v - ah) >> 16);
}

// ---------------------------------------------------------------------------
// pack_kernel: thread per fragment-row (nt,kc,l) handling e=0..7.
// Reads: 8 x 4B at 1KB stride; stores: two CONTIGUOUS 16B bf16x8 stores.
// ushort index ((nt*KC+kc)*64 + l)*8 + e,
// value = split_bf16(W[(kc*32 + (l>>4)*8 + e)*256 + nt*16 + (l&15)]).
// Region layout (ushort offsets): W1h:0 W1l:8192; layer ly in {0,1,2}:
//   h at 16384 + ly*131072, l = h + 65536
// ---------------------------------------------------------------------------
__global__ __launch_bounds__(256) void pack_kernel(
    const float* __restrict__ W1, const float* __restrict__ W2,
    const float* __restrict__ W3, const float* __restrict__ W4,
    unsigned short* __restrict__ pk)
{
    int idx = blockIdx.x * 256 + threadIdx.x;   // 0..25599
    if (idx >= 25600) return;
    const float* src;
    unsigned short *dh, *dl;
    int nt, kc, l, KC;
    if (idx < 1024) {                            // W1: K=32, KC=1
        src = W1; dh = pk; dl = pk + 8192; KC = 1;
        nt = idx >> 6; kc = 0; l = idx & 63;
    } else {                                     // W2..W4: K=256, KC=8
        int t2 = idx - 1024;
        int ly = t2 >> 13;                       // /8192
        int r2 = t2 & 8191;
        src = (ly == 0) ? W2 : (ly == 1) ? W3 : W4;
        dh = pk + 16384 + ly * 131072;
        dl = dh + 65536;
        KC = 8;
        nt = r2 >> 9; kc = (r2 >> 6) & 7; l = r2 & 63;
    }
    int lr = l & 15, lq = l >> 4;
    int n = nt * 16 + lr;
    bf16x8 hv, lv;
    #pragma unroll
    for (int e = 0; e < 8; e++) {
        int k = kc * 32 + lq * 8 + e;
        float v = src[k * 256 + n];
        unsigned short hb, lb;
        split_bf16(v, hb, lb);
        hv[e] = (short)hb; lv[e] = (short)lb;
    }
    int base = ((nt * KC + kc) * 64 + l) * 8;
    *(bf16x8*)(dh + base) = hv;
    *(bf16x8*)(dl + base) = lv;
}

// ---------------------------------------------------------------------------
// mlp_mfma_kernel v4: fused 5-layer MLP via split-bf16 MFMA
// (Ah*Bh + Ah*Bl + Al*Bh, fp32 accumulate).
// v4 change: per-block KC ROTATION. Theory: all 256 CUs stream the SAME
// weight addresses in lockstep -> same-L2-slice request storms serialize
// (contention limit, volume-invariant -- matches R2 vs R3: 205 vs 410 MB,
// identical 75us). kc = (kci + blockIdx.x) & 7 de-phases blocks so any
// instant spreads reads across the layer's full 256KB. Applied identically
// to LDS A-read and global B-read (accumulation order changes only ->
// fp32 rounding-level output shift).
// 32 rows/block, grid 512, 8 waves; wave wv owns n-tiles {2wv,2wv+1}.
// LDS XOR swizzle byte^=((row&7)<<4) keeps b128 A-reads conflict-free.
// ---------------------------------------------------------------------------
__global__ __launch_bounds__(512) void mlp_mfma_kernel(
    const float* __restrict__ z,
    const unsigned short* __restrict__ pk,
    const float* __restrict__ b1, const float* __restrict__ b2,
    const float* __restrict__ b3, const float* __restrict__ b4,
    const float* __restrict__ W5, const float* __restrict__ b5,
    float* __restrict__ gen)
{
    __shared__ __align__(16) unsigned short Hh[32 * 256];   // 16 KB
    __shared__ __align__(16) unsigned short Hl[32 * 256];   // 16 KB

    const int t  = threadIdx.x;
    const int l  = t & 63;
    const int wv = t >> 6;          // 0..7: owns n-tiles {2wv, 2wv+1}
    const int lr = l & 15;          // fragment m (A) / n (B,D) index
    const int lq = l >> 4;          // 0..3: k-subblock / D row group
    const int row0 = blockIdx.x * 32;
    const int bro  = blockIdx.x & 7;   // per-block kc rotation offset

    f32x4 acc[2][2];

    // ---------------- layer 1 (32 -> 256), K fits one MFMA ----------------
    {
        bf16x8 ah[2], al[2];
        #pragma unroll
        for (int m = 0; m < 2; m++) {
            const float* zp = z + (row0 + m * 16 + lr) * 32 + lq * 8;
            f32x4 z0 = *(const f32x4*)(zp);
            f32x4 z1 = *(const f32x4*)(zp + 4);
            #pragma unroll
            for (int e = 0; e < 8; e++) {
                float v = (e < 4) ? z0[e] : z1[e - 4];
                unsigned short hb, lb;
                split_bf16(v, hb, lb);
                ah[m][e] = (short)hb; al[m][e] = (short)lb;
            }
        }
        #pragma unroll
        for (int n2 = 0; n2 < 2; n2++) {
            float bv = b1[wv * 32 + n2 * 16 + lr];
            #pragma unroll
            for (int m = 0; m < 2; m++) acc[m][n2] = (f32x4){bv, bv, bv, bv};
        }
        const bf16x8* B1h = (const bf16x8*)(pk);
        const bf16x8* B1l = (const bf16x8*)(pk + 8192);
        #pragma unroll
        for (int n2 = 0; n2 < 2; n2++) {
            int nt = wv * 2 + n2;
            bf16x8 bh = B1h[nt * 64 + l];
            bf16x8 bl = B1l[nt * 64 + l];
            #pragma unroll
            for (int m = 0; m < 2; m++) {
                acc[m][n2] = mfma_bf16(ah[m], bh, acc[m][n2]);
                acc[m][n2] = mfma_bf16(ah[m], bl, acc[m][n2]);
                acc[m][n2] = mfma_bf16(al[m], bh, acc[m][n2]);
            }
        }
        // D layout (verified m89): col = lane&15, row = (lane>>4)*4 + r
        #pragma unroll
        for (int m = 0; m < 2; m++) {
            #pragma unroll
            for (int n2 = 0; n2 < 2; n2++) {
                #pragma unroll
                for (int r = 0; r < 4; r++) {
                    float v = selu_f(acc[m][n2][r]);
                    int rowo = m * 16 + lq * 4 + r;
                    int n = wv * 32 + n2 * 16 + lr;
                    int o = (2 * n) ^ ((rowo & 7) << 4);
                    unsigned short hb, lb;
                    split_bf16(v, hb, lb);
                    Hh[rowo * 256 + (o >> 1)] = hb;
                    Hl[rowo * 256 + (o >> 1)] = lb;
                }
            }
        }
    }
    __syncthreads();

    // ---------------- layers 2..4 (256 -> 256) ----------------
    #pragma unroll 1
    for (int ly = 0; ly < 3; ly++) {
        const unsigned short* wbase = pk + 16384 + ly * 131072;
        const bf16x8* Bh = (const bf16x8*)(wbase);
        const bf16x8* Bl = (const bf16x8*)(wbase + 65536);
        const float* bb = (ly == 0) ? b2 : (ly == 1) ? b3 : b4;
        #pragma unroll
        for (int n2 = 0; n2 < 2; n2++) {
            float bv = bb[wv * 32 + n2 * 16 + lr];
            #pragma unroll
            for (int m = 0; m < 2; m++) acc[m][n2] = (f32x4){bv, bv, bv, bv};
        }
        #pragma unroll 4
        for (int kci = 0; kci < 8; kci++) {
            int kc = (kci + bro) & 7;        // de-phased across blocks
            bf16x8 ah[2], al[2];
            #pragma unroll
            for (int m = 0; m < 2; m++) {
                int arow = m * 16 + lr;
                int o = (kc * 64 + lq * 16) ^ ((arow & 7) << 4);
                ah[m] = *(const bf16x8*)(Hh + arow * 256 + (o >> 1));
                al[m] = *(const bf16x8*)(Hl + arow * 256 + (o >> 1));
            }
            #pragma unroll
            for (int n2 = 0; n2 < 2; n2++) {
                bf16x8 bh = Bh[((wv * 2 + n2) * 8 + kc) * 64 + l];
                bf16x8 bl = Bl[((wv * 2 + n2) * 8 + kc) * 64 + l];
                #pragma unroll
                for (int m = 0; m < 2; m++) {
                    acc[m][n2] = mfma_bf16(ah[m], bh, acc[m][n2]);
                    acc[m][n2] = mfma_bf16(ah[m], bl, acc[m][n2]);
                    acc[m][n2] = mfma_bf16(al[m], bh, acc[m][n2]);
                }
            }
        }
        __syncthreads();   // all waves done READING H before anyone overwrites
        #pragma unroll
        for (int m = 0; m < 2; m++) {
            #pragma unroll
            for (int n2 = 0; n2 < 2; n2++) {
                #pragma unroll
                for (int r = 0; r < 4; r++) {
                    float v = selu_f(acc[m][n2][r]);
                    int rowo = m * 16 + lq * 4 + r;
                    int n = wv * 32 + n2 * 16 + lr;
                    int o = (2 * n) ^ ((rowo & 7) << 4);
                    unsigned short hb, lb;
                    split_bf16(v, hb, lb);
                    Hh[rowo * 256 + (o >> 1)] = hb;
                    Hl[rowo * 256 + (o >> 1)] = lb;
                }
            }
        }
        __syncthreads();   // writes visible before next layer's reads
    }

    // ---------------- layer 5 (256 -> 2), VALU, 64 threads ----------------
    if (t < 64) {
        int row = t & 31;
        int d = t >> 5;
        float sum = b5[d];
        #pragma unroll 4
        for (int k = 0; k < 256; k += 8) {
            int o = (2 * k) ^ ((row & 7) << 4);
            bf16x8 hh = *(const bf16x8*)(Hh + row * 256 + (o >> 1));
            bf16x8 ll = *(const bf16x8*)(Hl + row * 256 + (o >> 1));
            #pragma unroll
            for (int e = 0; e < 8; e++) {
                float hv = __uint_as_float(((unsigned)(unsigned short)hh[e]) << 16)
                         + __uint_as_float(((unsigned)(unsigned short)ll[e]) << 16);
                sum = fmaf(hv, W5[(k + e) * 2 + d], sum);
            }
        }
        gen[(row0 + row) * 2 + d] = sum;
    }
}

// ---------------------------------------------------------------------------
// Fallback fp32 MLP — used only if workspace too small for packed weights.
// ---------------------------------------------------------------------------
__global__ __launch_bounds__(1024) void mlp_kernel(
    const float* __restrict__ z,
    const float* __restrict__ W1, const float* __restrict__ b1,
    const float* __restrict__ W2, const float* __restrict__ b2,
    const float* __restrict__ W3, const float* __restrict__ b3,
    const float* __restrict__ W4, const float* __restrict__ b4,
    const float* __restrict__ W5, const float* __restrict__ b5,
    float* __restrict__ gen)
{
    __shared__ float h[256 * 64];

    const int t = threadIdx.x;
    const int r = t & 63;
    const int w = __builtin_amdgcn_readfirstlane(t >> 6);
    const int c0 = w * 16;
    const int row0 = blockIdx.x * 64;

    #pragma unroll
    for (int e = 0; e < 2; e++) {
        int f  = t + e * 1024;
        int rz = f >> 5;
        int kz = f & 31;
        h[kz * 64 + rz] = z[(row0 + rz) * 32 + kz];
    }
    __syncthreads();

    float acc[16];

    #pragma unroll
    for (int j = 0; j < 16; j++) acc[j] = b1[c0 + j];
    #pragma unroll 8
    for (int k = 0; k < 32; k++) {
        float hv = h[k * 64 + r];
        const float* Wr = W1 + k * 256 + c0;
        #pragma unroll
        for (int j = 0; j < 16; j++) acc[j] = fmaf(hv, Wr[j], acc[j]);
    }
    __syncthreads();
    #pragma unroll
    for (int j = 0; j < 16; j++) h[(c0 + j) * 64 + r] = selu_f(acc[j]);
    __syncthreads();

    for (int layer = 0; layer < 3; layer++) {
        const float* W = (layer == 0) ? W2 : (layer == 1) ? W3 : W4;
        const float* b = (layer == 0) ? b2 : (layer == 1) ? b3 : b4;
        #pragma unroll
        for (int j = 0; j < 16; j++) acc[j] = b[c0 + j];
        #pragma unroll 4
        for (int k = 0; k < 256; k++) {
            float hv = h[k * 64 + r];
            const float* Wr = W + k * 256 + c0;
            #pragma unroll
            for (int j = 0; j < 16; j++) acc[j] = fmaf(hv, Wr[j], acc[j]);
        }
        __syncthreads();
        #pragma unroll
        for (int j = 0; j < 16; j++) h[(c0 + j) * 64 + r] = selu_f(acc[j]);
        __syncthreads();
    }

    float p0 = 0.f, p1 = 0.f;
    #pragma unroll
    for (int kk = 0; kk < 16; kk++) {
        int k = c0 + kk;
        float hv = h[k * 64 + r];
        p0 = fmaf(hv, W5[k * 2 + 0], p0);
        p1 = fmaf(hv, W5[k * 2 + 1], p1);
    }
    __syncthreads();
    h[(0 * 16 + w) * 64 + r] = p0;
    h[(1 * 16 + w) * 64 + r] = p1;
    __syncthreads();
    if (t < 128) {
        int d  = t >> 6;
        int rr = t & 63;
        float sum = b5[d];
        #pragma unroll
        for (int ss = 0; ss < 16; ss++) sum += h[(d * 16 + ss) * 64 + rr];
        gen[(row0 + rr) * 2 + d] = sum;
    }
}

// ---------------------------------------------------------------------------
// Kernel B: SINGLE-PASS softmin-distance energy, fp32 in/out.
// row_off-chunked (4 x 4096 rows this round) to surface mlp in rocprof top-5.
// Inner loop and per-row math UNCHANGED (bit-identical results).
// ---------------------------------------------------------------------------
__global__ __launch_bounds__(512) void energy_kernel(
    const float* __restrict__ gen,
    const float* __restrict__ pos,
    float* __restrict__ out,
    int row_off)
{
    __shared__ float4 sp[512];   // 1024 pos points
    __shared__ float4 sg[512];   // 1024 gen points

    const int t  = threadIdx.x;
    const int s  = t & 31;       // lane within row-group
    const int rl = t >> 5;       // 0..15 row within block
    const int i  = row_off + blockIdx.x * 16 + rl;
    const int diagBase = ((row_off + blockIdx.x * 16) >> 10) << 10;   // block-uniform

    const float2 q = ((const float2*)gen)[i];

    const float cL2 = 28.853900817779268f;   // 1/(T*ln2) = 20*log2(e)
    const float Tl2 = 0.034657359027997264f; // T*ln2
    const float cB  = 57.707801635558536f;   // cL2 * B, B = 2.0

    float p0 = 0.f, p1 = 0.f, n0 = 0.f, n1 = 0.f;

    for (int base = 0; base < N_PTS; base += 1024) {
        __syncthreads();
        sp[t] = ((const float4*)pos)[base / 2 + t];
        sg[t] = ((const float4*)gen)[base / 2 + t];
        __syncthreads();
        if (base == diagBase) {
            #pragma unroll 4
            for (int u = 0; u < 16; u++) {
                int j = base + 2 * (s + 32 * u);
                float4 pp = sp[s + 32 * u];
                float4 gg = sg[s + 32 * u];
                float dx = q.x - pp.x, dy = q.y - pp.y;
                float d  = fast_sqrtf(fmaf(dx, dx, dy * dy));
                p0 += fast_exp2f(fmaf(-cL2, d, cB));
                dx = q.x - pp.z; dy = q.y - pp.w;
                d  = fast_sqrtf(fmaf(dx, dx, dy * dy));
                p1 += fast_exp2f(fmaf(-cL2, d, cB));
                dx = q.x - gg.x; dy = q.y - gg.y;
                d  = fast_sqrtf(fmaf(dx, dx, dy * dy));
                float e0 = fast_exp2f(fmaf(-cL2, d, cB));
                n0 += (j == i) ? 0.f : e0;
                dx = q.x - gg.z; dy = q.y - gg.w;
                d  = fast_sqrtf(fmaf(dx, dx, dy * dy));
                float e1 = fast_exp2f(fmaf(-cL2, d, cB));
                n1 += (j + 1 == i) ? 0.f : e1;
            }
        } else {
            #pragma unroll 4
            for (int u = 0; u < 16; u++) {
                float4 pp = sp[s + 32 * u];
                float4 gg = sg[s + 32 * u];
                float dx = q.x - pp.x, dy = q.y - pp.y;
                float d  = fast_sqrtf(fmaf(dx, dx, dy * dy));
                p0 += fast_exp2f(fmaf(-cL2, d, cB));
                dx = q.x - pp.z; dy = q.y - pp.w;
                d  = fast_sqrtf(fmaf(dx, dx, dy * dy));
                p1 += fast_exp2f(fmaf(-cL2, d, cB));
                dx = q.x - gg.x; dy = q.y - gg.y;
                d  = fast_sqrtf(fmaf(dx, dx, dy * dy));
                n0 += fast_exp2f(fmaf(-cL2, d, cB));
                dx = q.x - gg.z; dy = q.y - gg.w;
                d  = fast_sqrtf(fmaf(dx, dx, dy * dy));
                n1 += fast_exp2f(fmaf(-cL2, d, cB));
            }
        }
    }

    float sump = p0 + p1;
    float sumn = n0 + n1;
    #pragma unroll
    for (int m = 1; m < 32; m <<= 1) {
        sump += __shfl_xor(sump, m, 32);
        sumn += __shfl_xor(sumn, m, 32);
    }

    if (s == 0) {
        out[i] = Tl2 * (fast_log2f(sumn) - fast_log2f(sump));
    }
}

// ---------------------------------------------------------------------------
extern "C" void kernel_launch(void* const* d_in, const int* in_sizes, int n_in,
                              void* d_out, int out_size, void* d_ws, size_t ws_size,
                              hipStream_t stream) {
    const float* pos = (const float*)d_in[0];
    const float* z   = (const float*)d_in[1];
    const float* W1  = (const float*)d_in[2];
    const float* b1  = (const float*)d_in[3];
    const float* W2  = (const float*)d_in[4];
    const float* b2  = (const float*)d_in[5];
    const float* W3  = (const float*)d_in[6];
    const float* b3  = (const float*)d_in[7];
    const float* W4  = (const float*)d_in[8];
    const float* b4  = (const float*)d_in[9];
    const float* W5  = (const float*)d_in[10];
    const float* b5  = (const float*)d_in[11];

    float* gen = (float*)d_ws;                               // 16384 x 2 fp32
    unsigned short* pk = (unsigned short*)((char*)d_ws + 131072);
    float* outp = (float*)d_out;
    const size_t WS_NEEDED = 131072 + (size_t)409600 * 2;    // gen + packed W

    if (ws_size >= WS_NEEDED) {
        pack_kernel<<<100, 256, 0, stream>>>(W1, W2, W3, W4, pk);
        mlp_mfma_kernel<<<N_PTS / 32, 512, 0, stream>>>(z, pk, b1, b2, b3, b4,
                                                        W5, b5, gen);
    } else {
        mlp_kernel<<<N_PTS / 64, 1024, 0, stream>>>(z, W1, b1, W2, b2, W3, b3,
                                                    W4, b4, W5, b5, gen);
    }
    // 4-way row split: each chunk = 256 blocks. Diagnostic round — chunks
    // (~45-50us) sit below mlp (~75us if unfixed) so mlp surfaces in top-5.
    energy_kernel<<<N_PTS / 64, 512, 0, stream>>>(gen, pos, outp, 0);
    energy_kernel<<<N_PTS / 64, 512, 0, stream>>>(gen, pos, outp, 4096);
    energy_kernel<<<N_PTS / 64, 512, 0, stream>>>(gen, pos, outp, 8192);
    energy_kernel<<<N_PTS / 64, 512, 0, stream>>>(gen, pos, outp, 12288);
}

// Round 7
// 237.693 us; speedup vs baseline: 2.1635x; 1.1409x over previous
//
#include <hip/hip_runtime.h>
#include <hip/hip_bf16.h>

#define N_PTS 16384
#define TEMP_F 0.05f

typedef __attribute__((ext_vector_type(8))) short bf16x8;
typedef __attribute__((ext_vector_type(4))) float f32x4;

__device__ __forceinline__ float selu_f(float x) {
    const float scale = 1.0507009873554805f;
    const float alpha = 1.6732632423543772f;
    return x > 0.f ? scale * x : scale * alpha * (__expf(x) - 1.f);
}

__device__ __forceinline__ float fast_sqrtf(float x) {
#if __has_builtin(__builtin_amdgcn_sqrtf)
    return __builtin_amdgcn_sqrtf(x);   // v_sqrt_f32
#else
    return sqrtf(x);
#endif
}

__device__ __forceinline__ float fast_exp2f(float x) {
#if __has_builtin(__builtin_amdgcn_exp2f)
    return __builtin_amdgcn_exp2f(x);   // v_exp_f32
#else
    return exp2f(x);
#endif
}

__device__ __forceinline__ float fast_log2f(float x) {
#if __has_builtin(__builtin_amdgcn_logf)
    return __builtin_amdgcn_logf(x);    // v_log_f32
#else
    return log2f(x);
#endif
}

__device__ __forceinline__ f32x4 mfma_bf16(bf16x8 a, bf16x8 b, f32x4 c) {
    return __builtin_amdgcn_mfma_f32_16x16x32_bf16(a, b, c, 0, 0, 0);
}

// split fp32 v into truncated-bf16 hi + bf16(residual) lo; hi+lo ~ 16-bit mantissa
__device__ __forceinline__ void split_bf16(float v, unsigned short& hi, unsigned short& lo) {
    unsigned u = __float_as_uint(v);
    hi = (unsigned short)(u >> 16);
    float ah = __uint_as_float(u & 0xFFFF0000u);
    lo = (unsigned short)(__float_as_uint(v - ah) >> 16);
}

// ---------------------------------------------------------------------------
// pack_kernel: thread per fragment-row (nt,kc,l) handling e=0..7.
// ushort index ((nt*KC+kc)*64 + l)*8 + e,
// value = split_bf16(W[(kc*32 + (l>>4)*8 + e)*256 + nt*16 + (l&15)]).
// Region layout (ushort offsets): W1h:0 W1l:8192; layer ly in {0,1,2}:
//   h at 16384 + ly*131072, l = h + 65536
// ---------------------------------------------------------------------------
__global__ __launch_bounds__(256) void pack_kernel(
    const float* __restrict__ W1, const float* __restrict__ W2,
    const float* __restrict__ W3, const float* __restrict__ W4,
    unsigned short* __restrict__ pk)
{
    int idx = blockIdx.x * 256 + threadIdx.x;   // 0..25599
    if (idx >= 25600) return;
    const float* src;
    unsigned short *dh, *dl;
    int nt, kc, l, KC;
    if (idx < 1024) {                            // W1: K=32, KC=1
        src = W1; dh = pk; dl = pk + 8192; KC = 1;
        nt = idx >> 6; kc = 0; l = idx & 63;
    } else {                                     // W2..W4: K=256, KC=8
        int t2 = idx - 1024;
        int ly = t2 >> 13;                       // /8192
        int r2 = t2 & 8191;
        src = (ly == 0) ? W2 : (ly == 1) ? W3 : W4;
        dh = pk + 16384 + ly * 131072;
        dl = dh + 65536;
        KC = 8;
        nt = r2 >> 9; kc = (r2 >> 6) & 7; l = r2 & 63;
    }
    int lr = l & 15, lq = l >> 4;
    int n = nt * 16 + lr;
    bf16x8 hv, lv;
    #pragma unroll
    for (int e = 0; e < 8; e++) {
        int k = kc * 32 + lq * 8 + e;
        float v = src[k * 256 + n];
        unsigned short hb, lb;
        split_bf16(v, hb, lb);
        hv[e] = (short)hb; lv[e] = (short)lb;
    }
    int base = ((nt * KC + kc) * 64 + l) * 8;
    *(bf16x8*)(dh + base) = hv;
    *(bf16x8*)(dl + base) = lv;
}

// ---------------------------------------------------------------------------
// mlp_mfma_kernel v5: fused 5-layer MLP via split-bf16 MFMA
// (Ah*Bh + Ah*Bl + Al*Bh, fp32 accumulate).
// v5 change: DUAL de-phasing of the weight stream across blocks (lockstep
// same-address contention is the only lever that has moved this kernel):
//   kc rotation  (R6, confirmed ~-20us): kc = (kci + (b&7)) & 7
//   nt rotation  (new):   wave wv handles n-pair wp = (wv + (b>>3)) & 7
// 64 distinct (kc,nt) phase combos across 512 blocks -> at any instant the
// grid spreads over the full 256KB layer instead of 1/8. Pure relabeling of
// wave->column assignment; per-column compute sequence identical to v4 ->
// BIT-IDENTICAL output (absmax must stay 0.0009765625).
// 32 rows/block, grid 512, 8 waves; 12 MFMA/kc/wave.
// LDS XOR swizzle byte^=((row&7)<<4) keeps b128 A-reads conflict-free.
// ---------------------------------------------------------------------------
__global__ __launch_bounds__(512) void mlp_mfma_kernel(
    const float* __restrict__ z,
    const unsigned short* __restrict__ pk,
    const float* __restrict__ b1, const float* __restrict__ b2,
    const float* __restrict__ b3, const float* __restrict__ b4,
    const float* __restrict__ W5, const float* __restrict__ b5,
    float* __restrict__ gen)
{
    __shared__ __align__(16) unsigned short Hh[32 * 256];   // 16 KB
    __shared__ __align__(16) unsigned short Hl[32 * 256];   // 16 KB

    const int t  = threadIdx.x;
    const int l  = t & 63;
    const int wv = t >> 6;          // 0..7
    const int lr = l & 15;          // fragment m (A) / n (B,D) index
    const int lq = l >> 4;          // 0..3: k-subblock / D row group
    const int row0 = blockIdx.x * 32;
    const int bro  = blockIdx.x & 7;                 // kc rotation
    const int wp   = (wv + (blockIdx.x >> 3)) & 7;   // n-pair rotation

    f32x4 acc[2][2];

    // ---------------- layer 1 (32 -> 256), K fits one MFMA ----------------
    {
        bf16x8 ah[2], al[2];
        #pragma unroll
        for (int m = 0; m < 2; m++) {
            const float* zp = z + (row0 + m * 16 + lr) * 32 + lq * 8;
            f32x4 z0 = *(const f32x4*)(zp);
            f32x4 z1 = *(const f32x4*)(zp + 4);
            #pragma unroll
            for (int e = 0; e < 8; e++) {
                float v = (e < 4) ? z0[e] : z1[e - 4];
                unsigned short hb, lb;
                split_bf16(v, hb, lb);
                ah[m][e] = (short)hb; al[m][e] = (short)lb;
            }
        }
        #pragma unroll
        for (int n2 = 0; n2 < 2; n2++) {
            float bv = b1[wp * 32 + n2 * 16 + lr];
            #pragma unroll
            for (int m = 0; m < 2; m++) acc[m][n2] = (f32x4){bv, bv, bv, bv};
        }
        const bf16x8* B1h = (const bf16x8*)(pk);
        const bf16x8* B1l = (const bf16x8*)(pk + 8192);
        #pragma unroll
        for (int n2 = 0; n2 < 2; n2++) {
            int nt = wp * 2 + n2;
            bf16x8 bh = B1h[nt * 64 + l];
            bf16x8 bl = B1l[nt * 64 + l];
            #pragma unroll
            for (int m = 0; m < 2; m++) {
                acc[m][n2] = mfma_bf16(ah[m], bh, acc[m][n2]);
                acc[m][n2] = mfma_bf16(ah[m], bl, acc[m][n2]);
                acc[m][n2] = mfma_bf16(al[m], bh, acc[m][n2]);
            }
        }
        // D layout (verified m89): col = lane&15, row = (lane>>4)*4 + r
        #pragma unroll
        for (int m = 0; m < 2; m++) {
            #pragma unroll
            for (int n2 = 0; n2 < 2; n2++) {
                #pragma unroll
                for (int r = 0; r < 4; r++) {
                    float v = selu_f(acc[m][n2][r]);
                    int rowo = m * 16 + lq * 4 + r;
                    int n = wp * 32 + n2 * 16 + lr;
                    int o = (2 * n) ^ ((rowo & 7) << 4);
                    unsigned short hb, lb;
                    split_bf16(v, hb, lb);
                    Hh[rowo * 256 + (o >> 1)] = hb;
                    Hl[rowo * 256 + (o >> 1)] = lb;
                }
            }
        }
    }
    __syncthreads();

    // ---------------- layers 2..4 (256 -> 256) ----------------
    #pragma unroll 1
    for (int ly = 0; ly < 3; ly++) {
        const unsigned short* wbase = pk + 16384 + ly * 131072;
        const bf16x8* Bh = (const bf16x8*)(wbase);
        const bf16x8* Bl = (const bf16x8*)(wbase + 65536);
        const float* bb = (ly == 0) ? b2 : (ly == 1) ? b3 : b4;
        #pragma unroll
        for (int n2 = 0; n2 < 2; n2++) {
            float bv = bb[wp * 32 + n2 * 16 + lr];
            #pragma unroll
            for (int m = 0; m < 2; m++) acc[m][n2] = (f32x4){bv, bv, bv, bv};
        }
        #pragma unroll 4
        for (int kci = 0; kci < 8; kci++) {
            int kc = (kci + bro) & 7;        // de-phased across blocks
            bf16x8 ah[2], al[2];
            #pragma unroll
            for (int m = 0; m < 2; m++) {
                int arow = m * 16 + lr;
                int o = (kc * 64 + lq * 16) ^ ((arow & 7) << 4);
                ah[m] = *(const bf16x8*)(Hh + arow * 256 + (o >> 1));
                al[m] = *(const bf16x8*)(Hl + arow * 256 + (o >> 1));
            }
            #pragma unroll
            for (int n2 = 0; n2 < 2; n2++) {
                int nt = wp * 2 + n2;
                bf16x8 bh = Bh[(nt * 8 + kc) * 64 + l];
                bf16x8 bl = Bl[(nt * 8 + kc) * 64 + l];
                #pragma unroll
                for (int m = 0; m < 2; m++) {
                    acc[m][n2] = mfma_bf16(ah[m], bh, acc[m][n2]);
                    acc[m][n2] = mfma_bf16(ah[m], bl, acc[m][n2]);
                    acc[m][n2] = mfma_bf16(al[m], bh, acc[m][n2]);
                }
            }
        }
        __syncthreads();   // all waves done READING H before anyone overwrites
        #pragma unroll
        for (int m = 0; m < 2; m++) {
            #pragma unroll
            for (int n2 = 0; n2 < 2; n2++) {
                #pragma unroll
                for (int r = 0; r < 4; r++) {
                    float v = selu_f(acc[m][n2][r]);
                    int rowo = m * 16 + lq * 4 + r;
                    int n = wp * 32 + n2 * 16 + lr;
                    int o = (2 * n) ^ ((rowo & 7) << 4);
                    unsigned short hb, lb;
                    split_bf16(v, hb, lb);
                    Hh[rowo * 256 + (o >> 1)] = hb;
                    Hl[rowo * 256 + (o >> 1)] = lb;
                }
            }
        }
        __syncthreads();   // writes visible before next layer's reads
    }

    // ---------------- layer 5 (256 -> 2), VALU, 64 threads ----------------
    if (t < 64) {
        int row = t & 31;
        int d = t >> 5;
        float sum = b5[d];
        #pragma unroll 4
        for (int k = 0; k < 256; k += 8) {
            int o = (2 * k) ^ ((row & 7) << 4);
            bf16x8 hh = *(const bf16x8*)(Hh + row * 256 + (o >> 1));
            bf16x8 ll = *(const bf16x8*)(Hl + row * 256 + (o >> 1));
            #pragma unroll
            for (int e = 0; e < 8; e++) {
                float hv = __uint_as_float(((unsigned)(unsigned short)hh[e]) << 16)
                         + __uint_as_float(((unsigned)(unsigned short)ll[e]) << 16);
                sum = fmaf(hv, W5[(k + e) * 2 + d], sum);
            }
        }
        gen[(row0 + row) * 2 + d] = sum;
    }
}

// ---------------------------------------------------------------------------
// Fallback fp32 MLP — used only if workspace too small for packed weights.
// ---------------------------------------------------------------------------
__global__ __launch_bounds__(1024) void mlp_kernel(
    const float* __restrict__ z,
    const float* __restrict__ W1, const float* __restrict__ b1,
    const float* __restrict__ W2, const float* __restrict__ b2,
    const float* __restrict__ W3, const float* __restrict__ b3,
    const float* __restrict__ W4, const float* __restrict__ b4,
    const float* __restrict__ W5, const float* __restrict__ b5,
    float* __restrict__ gen)
{
    __shared__ float h[256 * 64];

    const int t = threadIdx.x;
    const int r = t & 63;
    const int w = __builtin_amdgcn_readfirstlane(t >> 6);
    const int c0 = w * 16;
    const int row0 = blockIdx.x * 64;

    #pragma unroll
    for (int e = 0; e < 2; e++) {
        int f  = t + e * 1024;
        int rz = f >> 5;
        int kz = f & 31;
        h[kz * 64 + rz] = z[(row0 + rz) * 32 + kz];
    }
    __syncthreads();

    float acc[16];

    #pragma unroll
    for (int j = 0; j < 16; j++) acc[j] = b1[c0 + j];
    #pragma unroll 8
    for (int k = 0; k < 32; k++) {
        float hv = h[k * 64 + r];
        const float* Wr = W1 + k * 256 + c0;
        #pragma unroll
        for (int j = 0; j < 16; j++) acc[j] = fmaf(hv, Wr[j], acc[j]);
    }
    __syncthreads();
    #pragma unroll
    for (int j = 0; j < 16; j++) h[(c0 + j) * 64 + r] = selu_f(acc[j]);
    __syncthreads();

    for (int layer = 0; layer < 3; layer++) {
        const float* W = (layer == 0) ? W2 : (layer == 1) ? W3 : W4;
        const float* b = (layer == 0) ? b2 : (layer == 1) ? b3 : b4;
        #pragma unroll
        for (int j = 0; j < 16; j++) acc[j] = b[c0 + j];
        #pragma unroll 4
        for (int k = 0; k < 256; k++) {
            float hv = h[k * 64 + r];
            const float* Wr = W + k * 256 + c0;
            #pragma unroll
            for (int j = 0; j < 16; j++) acc[j] = fmaf(hv, Wr[j], acc[j]);
        }
        __syncthreads();
        #pragma unroll
        for (int j = 0; j < 16; j++) h[(c0 + j) * 64 + r] = selu_f(acc[j]);
        __syncthreads();
    }

    float p0 = 0.f, p1 = 0.f;
    #pragma unroll
    for (int kk = 0; kk < 16; kk++) {
        int k = c0 + kk;
        float hv = h[k * 64 + r];
        p0 = fmaf(hv, W5[k * 2 + 0], p0);
        p1 = fmaf(hv, W5[k * 2 + 1], p1);
    }
    __syncthreads();
    h[(0 * 16 + w) * 64 + r] = p0;
    h[(1 * 16 + w) * 64 + r] = p1;
    __syncthreads();
    if (t < 128) {
        int d  = t >> 6;
        int rr = t & 63;
        float sum = b5[d];
        #pragma unroll
        for (int ss = 0; ss < 16; ss++) sum += h[(d * 16 + ss) * 64 + rr];
        gen[(row0 + rr) * 2 + d] = sum;
    }
}

// ---------------------------------------------------------------------------
// Kernel B: SINGLE-PASS softmin-distance energy, fp32 in/out.
// Merged back to ONE dispatch (R6 4-way split cost ~43us in occupancy/tail;
// this exact config measured 151.8us in R0). Math unchanged.
// ---------------------------------------------------------------------------
__global__ __launch_bounds__(512) void energy_kernel(
    const float* __restrict__ gen,
    const float* __restrict__ pos,
    float* __restrict__ out)
{
    __shared__ float4 sp[512];   // 1024 pos points
    __shared__ float4 sg[512];   // 1024 gen points

    const int t  = threadIdx.x;
    const int s  = t & 31;       // lane within row-group
    const int rl = t >> 5;       // 0..15 row within block
    const int i  = blockIdx.x * 16 + rl;
    const int diagBase = ((blockIdx.x * 16) >> 10) << 10;   // block-uniform

    const float2 q = ((const float2*)gen)[i];

    const float cL2 = 28.853900817779268f;   // 1/(T*ln2) = 20*log2(e)
    const float Tl2 = 0.034657359027997264f; // T*ln2
    const float cB  = 57.707801635558536f;   // cL2 * B, B = 2.0

    float p0 = 0.f, p1 = 0.f, n0 = 0.f, n1 = 0.f;

    for (int base = 0; base < N_PTS; base += 1024) {
        __syncthreads();
        sp[t] = ((const float4*)pos)[base / 2 + t];
        sg[t] = ((const float4*)gen)[base / 2 + t];
        __syncthreads();
        if (base == diagBase) {
            #pragma unroll 4
            for (int u = 0; u < 16; u++) {
                int j = base + 2 * (s + 32 * u);
                float4 pp = sp[s + 32 * u];
                float4 gg = sg[s + 32 * u];
                float dx = q.x - pp.x, dy = q.y - pp.y;
                float d  = fast_sqrtf(fmaf(dx, dx, dy * dy));
                p0 += fast_exp2f(fmaf(-cL2, d, cB));
                dx = q.x - pp.z; dy = q.y - pp.w;
                d  = fast_sqrtf(fmaf(dx, dx, dy * dy));
                p1 += fast_exp2f(fmaf(-cL2, d, cB));
                dx = q.x - gg.x; dy = q.y - gg.y;
                d  = fast_sqrtf(fmaf(dx, dx, dy * dy));
                float e0 = fast_exp2f(fmaf(-cL2, d, cB));
                n0 += (j == i) ? 0.f : e0;
                dx = q.x - gg.z; dy = q.y - gg.w;
                d  = fast_sqrtf(fmaf(dx, dx, dy * dy));
                float e1 = fast_exp2f(fmaf(-cL2, d, cB));
                n1 += (j + 1 == i) ? 0.f : e1;
            }
        } else {
            #pragma unroll 4
            for (int u = 0; u < 16; u++) {
                float4 pp = sp[s + 32 * u];
                float4 gg = sg[s + 32 * u];
                float dx = q.x - pp.x, dy = q.y - pp.y;
                float d  = fast_sqrtf(fmaf(dx, dx, dy * dy));
                p0 += fast_exp2f(fmaf(-cL2, d, cB));
                dx = q.x - pp.z; dy = q.y - pp.w;
                d  = fast_sqrtf(fmaf(dx, dx, dy * dy));
                p1 += fast_exp2f(fmaf(-cL2, d, cB));
                dx = q.x - gg.x; dy = q.y - gg.y;
                d  = fast_sqrtf(fmaf(dx, dx, dy * dy));
                n0 += fast_exp2f(fmaf(-cL2, d, cB));
                dx = q.x - gg.z; dy = q.y - gg.w;
                d  = fast_sqrtf(fmaf(dx, dx, dy * dy));
                n1 += fast_exp2f(fmaf(-cL2, d, cB));
            }
        }
    }

    float sump = p0 + p1;
    float sumn = n0 + n1;
    #pragma unroll
    for (int m = 1; m < 32; m <<= 1) {
        sump += __shfl_xor(sump, m, 32);
        sumn += __shfl_xor(sumn, m, 32);
    }

    if (s == 0) {
        out[i] = Tl2 * (fast_log2f(sumn) - fast_log2f(sump));
    }
}

// ---------------------------------------------------------------------------
extern "C" void kernel_launch(void* const* d_in, const int* in_sizes, int n_in,
                              void* d_out, int out_size, void* d_ws, size_t ws_size,
                              hipStream_t stream) {
    const float* pos = (const float*)d_in[0];
    const float* z   = (const float*)d_in[1];
    const float* W1  = (const float*)d_in[2];
    const float* b1  = (const float*)d_in[3];
    const float* W2  = (const float*)d_in[4];
    const float* b2  = (const float*)d_in[5];
    const float* W3  = (const float*)d_in[6];
    const float* b3  = (const float*)d_in[7];
    const float* W4  = (const float*)d_in[8];
    const float* b4  = (const float*)d_in[9];
    const float* W5  = (const float*)d_in[10];
    const float* b5  = (const float*)d_in[11];

    float* gen = (float*)d_ws;                               // 16384 x 2 fp32
    unsigned short* pk = (unsigned short*)((char*)d_ws + 131072);
    float* outp = (float*)d_out;
    const size_t WS_NEEDED = 131072 + (size_t)409600 * 2;    // gen + packed W

    if (ws_size >= WS_NEEDED) {
        pack_kernel<<<100, 256, 0, stream>>>(W1, W2, W3, W4, pk);
        mlp_mfma_kernel<<<N_PTS / 32, 512, 0, stream>>>(z, pk, b1, b2, b3, b4,
                                                        W5, b5, gen);
    } else {
        mlp_kernel<<<N_PTS / 64, 1024, 0, stream>>>(z, W1, b1, W2, b2, W3, b3,
                                                    W4, b4, W5, b5, gen);
    }
    energy_kernel<<<N_PTS / 16, 512, 0, stream>>>(gen, pos, outp);
}